// Round 15
// baseline (148.472 us; speedup 1.0000x reference)
//
#include <hip/hip_runtime.h>
#include <hip/hip_bf16.h>

// Nav_64939905516231 (VIN value iteration), MI355X gfx950.
// B=64,H=W=64,dim_h=150,n_hat=8,n_act=4,K=10. fp32 in/out, maze int32.
// Collapses: r = conv5x5(m,W_eff)+b_eff (150ch folded); q_t = q0 + conv5x5(v,w).
// prep (1 blk) -> rq (r+q0) -> vi (10 fused steps + projection, redundant
// shrinking-halo compute, channel-split wave pairs + adjacent-row pairing).
// Facts: 1024-thr => VGPR 64 (GB spills); 512-thr => VGPR<=128 always; 200
// weight floats/lane spill, 100 fit. R13/R14 @OWN=16 (1 blk/CU, 2 waves/SIMD)
// both 47.8us with LDS+VALU each ~45-50% busy -> latency-exposed, occupancy-
// structure bound. ~75us of total is fixed harness floor (ws poison + ovh).
// R15: OWN=8, grid 512 = 2 blocks/CU -> 4 waves/SIMD (2x hiding) for 1.53x
// redundant work; LDS/block ~50KB so both blocks fit.

#define NHAT 8
#define DIMH 150

typedef float v2f __attribute__((ext_vector_type(2)));

// ---------------- prep: T[4][25] tap table + b_eff (1 block) ----------------
__global__ __launch_bounds__(128) void prep_kernel(
    const float* __restrict__ emb, const float* __restrict__ encode_w,
    const float* __restrict__ encode_b, const float* __restrict__ r_w,
    float* __restrict__ T, float* __restrict__ beff) {
  __shared__ float weff[2][25];
  int tid = threadIdx.x;
  if (tid < 50) {
    int i = tid / 25, k = tid % 25;
    float s = 0.f;
    for (int c = 0; c < DIMH; ++c)
      s += r_w[c] * encode_w[c * 50 + i * 25 + k];
    weff[i][k] = s;
  }
  if (tid == 64) {
    float s = 0.f;
    for (int c = 0; c < DIMH; ++c) s += r_w[c] * encode_b[c];
    *beff = s;
  }
  __syncthreads();
  if (tid < 100) {
    int val = tid / 25, k = tid % 25;
    float t = 0.f;
    if (val < 3) t = weff[0][k] * emb[val * 2] + weff[1][k] * emb[val * 2 + 1];
    T[val * 25 + k] = t;  // row 3 == 0 (padding sentinel)
  }
}

// ---------------- rq: r = table-conv(maze), q0 = conv5x5(r, q_w) -----------
__global__ __launch_bounds__(512) void rq_kernel(
    const int* __restrict__ maze, const float* __restrict__ Tg,
    const float* __restrict__ beffg, const float* __restrict__ q_w,
    float* __restrict__ q0g) {
  __shared__ float Ts[4][25];
  __shared__ float bsh;
  __shared__ v2f qw2[25][4];
  __shared__ unsigned char mzt[24][68];
  __shared__ float rt[20][68];

  int tid = threadIdx.x;
  int b = blockIdx.y, A0 = blockIdx.x * 16;

  if (tid < 100) Ts[tid / 25][tid % 25] = Tg[tid];
  if (tid == 100) bsh = *beffg;
  if (tid >= 128 && tid < 228) {
    int t2 = tid - 128;
    int k = t2 >> 2, j = t2 & 3;
    qw2[k][j] = (v2f){q_w[(2 * j) * 25 + k], q_w[(2 * j + 1) * 25 + k]};
  }
  for (int i = tid; i < 24 * 68; i += 512) {
    int mr = i / 68, mc = i % 68;
    int gy = A0 - 4 + mr, gx = mc - 2;
    unsigned char v = 3;
    if (gy >= 0 && gy < 64 && gx >= 0 && gx < 64)
      v = (unsigned char)maze[(b * 64 + gy) * 64 + gx];
    mzt[mr][mc] = v;
  }
  __syncthreads();
  // r tile rows [A0-2, A0+18): r(A0-2+rr, cc-2) taps mzt[rr+ky][cc-2+kx]
  for (int i = tid; i < 20 * 68; i += 512) {
    int rr = i / 68, cc = i % 68;
    int gy = A0 - 2 + rr, gx = cc - 2;
    float v = 0.f;
    if (gy >= 0 && gy < 64 && gx >= 0 && gx < 64) {
      v = bsh;
#pragma unroll
      for (int ky = 0; ky < 5; ++ky)
#pragma unroll
        for (int kx = 0; kx < 5; ++kx)
          v += Ts[mzt[rr + ky][cc - 2 + kx]][ky * 5 + kx];
    }
    rt[rr][cc] = v;
  }
  __syncthreads();
  for (int i = tid; i < 16 * 64; i += 512) {
    int ly = i >> 6, gx = i & 63;
    int gy = A0 + ly;
    v2f acc[4];
#pragma unroll
    for (int j = 0; j < 4; ++j) acc[j] = (v2f){0.f, 0.f};
#pragma unroll
    for (int ky = 0; ky < 5; ++ky)
#pragma unroll
      for (int kx = 0; kx < 5; ++kx) {
        int k = ky * 5 + kx;
        float vv = rt[ly + ky][gx + kx];
        v2f vv2 = (v2f){vv, vv};
#pragma unroll
        for (int j = 0; j < 4; ++j) acc[j] += qw2[k][j] * vv2;
      }
    float* dst = q0g + ((size_t)(b * 4096 + gy * 64 + gx)) * NHAT;
    ((float4*)dst)[0] = make_float4(acc[0].x, acc[0].y, acc[1].x, acc[1].y);
    ((float4*)dst)[1] = make_float4(acc[2].x, acc[2].y, acc[3].x, acc[3].y);
  }
}

// =============== vi: 10 fused VI steps + projection =================
// Block (512 thr = 8 waves) owns rows [a0, a0+8) of image b; grid 512 blocks
// = 2 blocks/CU -> 4 waves/SIMD. Wave = (slot = wave>>1 in 0..3, half =
// wave&1). Each wave-iter computes rows (r0, r0+1) for its 4 channels
// (100 weight floats, register/AGPR-resident); 6 input rows x 5 taps serve
// both rows. Halves combine per row via LDS tmp at the step barrier.
// lr = r - a0 + 20, vbuf rows [0,49); tmp row = lr - 2 in [0,44).
__global__ __launch_bounds__(512, 2) void vi_kernel(
    const float* __restrict__ q0g, const float* __restrict__ w,
    const float* __restrict__ fc_w, float* __restrict__ out) {
  __shared__ float vbuf[2][49][68];               // 26.6 KB
  __shared__ __align__(16) float tmp[44][2][64];  // 22.5 KB (reused for proj)
  __shared__ v2f wl2[25][4];

  int tid = threadIdx.x;
  int b = blockIdx.y, a0 = blockIdx.x * 8;
  int wave = tid >> 6, gx = tid & 63;
  int half = wave & 1, slot = wave >> 1;

  if (tid < 100) {
    int k = tid >> 2, j = tid & 3;
    wl2[k][j] = (v2f){w[(2 * j) * 25 + k], w[(2 * j + 1) * 25 + k]};
  }
  for (int i = tid; i < 2 * 49 * 68; i += 512) ((float*)vbuf)[i] = 0.f;
  __syncthreads();

  // this wave's 4 channels -> 50 v2f = 100 floats in registers/AGPRs
  v2f wr0[25], wr1[25];
#pragma unroll
  for (int k = 0; k < 25; ++k) {
    wr0[k] = wl2[k][2 * half];
    wr1[k] = wl2[k][2 * half + 1];
  }

  const float* q0b = q0g + (size_t)b * 4096 * NHAT;
  int cur = 0;

  // v0 = max_c q0 on [a0-20, a0+28): full 8ch per lane, waves stride 8 rows
  {
    int s = max(0, a0 - 20), e = min(64, a0 + 28);
    for (int r = s + wave; r < e; r += 8) {
      const float4* p = (const float4*)(q0b + ((size_t)r * 64 + gx) * NHAT);
      float4 f0 = p[0], f1 = p[1];
      float m = fmaxf(fmaxf(fmaxf(f0.x, f0.y), fmaxf(f0.z, f0.w)),
                      fmaxf(fmaxf(f1.x, f1.y), fmaxf(f1.z, f1.w)));
      vbuf[0][r - a0 + 20][gx + 2] = m;
    }
  }
  __syncthreads();

  for (int t = 1; t <= 9; ++t) {
    int hh = 2 * (10 - t);
    int s = max(0, a0 - hh), e = min(64, a0 + 8 + hh);
    // phase A: each wave -> half-max for row pair (r0, r0+1), its 4 channels
    for (int r0 = s + 2 * slot; r0 < e; r0 += 8) {
      int r1 = r0 + 1;  // may be >= e (write guarded)
      int lr0 = r0 - a0 + 20;
      const float4* p0 =
          (const float4*)(q0b + ((size_t)r0 * 64 + gx) * NHAT + half * 4);
      float4 qa = *p0;
      float4 qb = make_float4(0.f, 0.f, 0.f, 0.f);
      if (r1 < e)
        qb = *(const float4*)(q0b + ((size_t)r1 * 64 + gx) * NHAT + half * 4);
      v2f A0 = (v2f){0.f, 0.f}, A1 = (v2f){0.f, 0.f};
      v2f B0 = (v2f){0.f, 0.f}, B1 = (v2f){0.f, 0.f};
      // 6 input rows serve both outputs: r0 uses jj=0..4, r1 uses jj=1..5
#pragma unroll
      for (int jj = 0; jj < 6; ++jj) {
        const float* row = &vbuf[cur][lr0 - 2 + jj][gx];
#pragma unroll
        for (int kx = 0; kx < 5; ++kx) {
          float vv = row[kx];
          v2f vv2 = (v2f){vv, vv};
          if (jj < 5) {
            int k = jj * 5 + kx;
            A0 += wr0[k] * vv2;
            A1 += wr1[k] * vv2;
          }
          if (jj >= 1) {
            int k = (jj - 1) * 5 + kx;
            B0 += wr0[k] * vv2;
            B1 += wr1[k] * vv2;
          }
        }
      }
      A0 += (v2f){qa.x, qa.y};
      A1 += (v2f){qa.z, qa.w};
      tmp[lr0 - 2][half][gx] = fmaxf(fmaxf(A0.x, A0.y), fmaxf(A1.x, A1.y));
      if (r1 < e) {
        B0 += (v2f){qb.x, qb.y};
        B1 += (v2f){qb.z, qb.w};
        tmp[lr0 - 1][half][gx] = fmaxf(fmaxf(B0.x, B0.y), fmaxf(B1.x, B1.y));
      }
    }
    __syncthreads();
    // phase B: combine halves -> vbuf[cur^1]
    int n = e - s;
    for (int idx = tid; idx < n * 64; idx += 512) {
      int rr = idx >> 6, px = idx & 63;
      int lr2 = s - a0 + 20 + rr;
      vbuf[cur ^ 1][lr2][px + 2] =
          fmaxf(tmp[lr2 - 2][0][px], tmp[lr2 - 2][1][px]);
    }
    __syncthreads();
    cur ^= 1;
  }

  // final step t=10 fused with projection: rows [a0, a0+8), one pair per slot
  float fcp[4][4];
#pragma unroll
  for (int a = 0; a < 4; ++a)
#pragma unroll
    for (int cc = 0; cc < 4; ++cc) fcp[a][cc] = fc_w[a * 8 + 4 * half + cc];
  float* proj = (float*)tmp;  // reused as proj[8][64][4] = 8 KB

  {
    int r0 = a0 + 2 * slot;
    int r1 = r0 + 1;
    int lr0 = r0 - a0 + 20;
    const float4* p0 =
        (const float4*)(q0b + ((size_t)r0 * 64 + gx) * NHAT + half * 4);
    float4 qa = *p0;
    float4 qb =
        *(const float4*)(q0b + ((size_t)r1 * 64 + gx) * NHAT + half * 4);
    v2f A0 = (v2f){0.f, 0.f}, A1 = (v2f){0.f, 0.f};
    v2f B0 = (v2f){0.f, 0.f}, B1 = (v2f){0.f, 0.f};
#pragma unroll
    for (int jj = 0; jj < 6; ++jj) {
      const float* row = &vbuf[cur][lr0 - 2 + jj][gx];
#pragma unroll
      for (int kx = 0; kx < 5; ++kx) {
        float vv = row[kx];
        v2f vv2 = (v2f){vv, vv};
        if (jj < 5) {
          int k = jj * 5 + kx;
          A0 += wr0[k] * vv2;
          A1 += wr1[k] * vv2;
        }
        if (jj >= 1) {
          int k = (jj - 1) * 5 + kx;
          B0 += wr0[k] * vv2;
          B1 += wr1[k] * vv2;
        }
      }
    }
    float q0v = A0.x + qa.x, q1v = A0.y + qa.y;
    float q2v = A1.x + qa.z, q3v = A1.y + qa.w;
    float4 pa;
    pa.x = fcp[0][0] * q0v + fcp[0][1] * q1v + fcp[0][2] * q2v + fcp[0][3] * q3v;
    pa.y = fcp[1][0] * q0v + fcp[1][1] * q1v + fcp[1][2] * q2v + fcp[1][3] * q3v;
    pa.z = fcp[2][0] * q0v + fcp[2][1] * q1v + fcp[2][2] * q2v + fcp[2][3] * q3v;
    pa.w = fcp[3][0] * q0v + fcp[3][1] * q1v + fcp[3][2] * q2v + fcp[3][3] * q3v;
    q0v = B0.x + qb.x; q1v = B0.y + qb.y;
    q2v = B1.x + qb.z; q3v = B1.y + qb.w;
    float4 pb;
    pb.x = fcp[0][0] * q0v + fcp[0][1] * q1v + fcp[0][2] * q2v + fcp[0][3] * q3v;
    pb.y = fcp[1][0] * q0v + fcp[1][1] * q1v + fcp[1][2] * q2v + fcp[1][3] * q3v;
    pb.z = fcp[2][0] * q0v + fcp[2][1] * q1v + fcp[2][2] * q2v + fcp[2][3] * q3v;
    pb.w = fcp[3][0] * q0v + fcp[3][1] * q1v + fcp[3][2] * q2v + fcp[3][3] * q3v;
    int i0 = 2 * slot, i1 = 2 * slot + 1;
    if (half == 1) {
      *(float4*)&proj[(i0 * 64 + gx) * 4] = pa;
      *(float4*)&proj[(i1 * 64 + gx) * 4] = pb;
    }
    __syncthreads();
    if (half == 0) {
      float4 oa = *(const float4*)&proj[(i0 * 64 + gx) * 4];
      float4 ob = *(const float4*)&proj[(i1 * 64 + gx) * 4];
      oa.x += pa.x; oa.y += pa.y; oa.z += pa.z; oa.w += pa.w;
      ob.x += pb.x; ob.y += pb.y; ob.z += pb.z; ob.w += pb.w;
      *(float4*)&out[((size_t)((b * 64 + r0) * 64 + gx)) * 4] = oa;
      *(float4*)&out[((size_t)((b * 64 + r1) * 64 + gx)) * 4] = ob;
    }
  }
}

extern "C" void kernel_launch(void* const* d_in, const int* in_sizes, int n_in,
                              void* d_out, int out_size, void* d_ws, size_t ws_size,
                              hipStream_t stream) {
  const int* maze = (const int*)d_in[0];
  const float* emb = (const float*)d_in[1];
  const float* encode_w = (const float*)d_in[2];
  const float* encode_b = (const float*)d_in[3];
  const float* r_w = (const float*)d_in[4];
  const float* q_w = (const float*)d_in[5];
  const float* w = (const float*)d_in[6];
  const float* fc_w = (const float*)d_in[7];
  float* out = (float*)d_out;

  float* wsf = (float*)d_ws;
  float* T = wsf;            // 100 floats
  float* beff = wsf + 100;   // 1 float
  float* q0 = wsf + 128;     // 8 MB

  prep_kernel<<<1, 128, 0, stream>>>(emb, encode_w, encode_b, r_w, T, beff);
  rq_kernel<<<dim3(4, 64), 512, 0, stream>>>(maze, T, beff, q_w, q0);
  vi_kernel<<<dim3(8, 64), 512, 0, stream>>>(q0, w, fc_w, out);
}

// Round 16
// 145.466 us; speedup vs baseline: 1.0207x; 1.0207x over previous
//
#include <hip/hip_runtime.h>
#include <hip/hip_bf16.h>

// Nav_64939905516231 (VIN value iteration), MI355X gfx950.
// B=64,H=W=64,dim_h=150,n_hat=8,n_act=4,K=10. fp32 in/out, maze int32.
// Collapses: r = conv5x5(m,W_eff)+b_eff (150ch folded); q_t = q0 + conv5x5(v,w).
// prep (1 blk) -> rq (r+q0) -> vi (10 fused steps + projection, redundant
// shrinking-halo compute, channel-split wave pairs + adjacent-row pairing).
// Facts: 1024-thr => VGPR 64 (GB spills); 512-thr => VGPR<=128 always; 200
// weight floats/lane spill, 100 fit. All 512-thr configs with LDS>=35KB show
// ~18% occupancy (1 blk/CU) -- R15 grid-512 proved 2x50KB does NOT co-reside:
// effective co-residency LDS budget ~64KB/CU. ~75us of total is fixed harness
// floor (ws poison fill + prep/rq + overheads).
// R16: LDS 50->27KB (tmp deleted: half0 writes vbuf[cur^1] direct; half1 RMWs
// after barrier with register-held hm[]); OWN=8 grid 512 -> 2 blk/CU ->
// 4 waves/SIMD. Tripwire: occupancy stuck at 18% falsifies the LDS-cap theory.

#define NHAT 8
#define DIMH 150

typedef float v2f __attribute__((ext_vector_type(2)));

// ---------------- prep: T[4][25] tap table + b_eff (1 block) ----------------
__global__ __launch_bounds__(128) void prep_kernel(
    const float* __restrict__ emb, const float* __restrict__ encode_w,
    const float* __restrict__ encode_b, const float* __restrict__ r_w,
    float* __restrict__ T, float* __restrict__ beff) {
  __shared__ float weff[2][25];
  int tid = threadIdx.x;
  if (tid < 50) {
    int i = tid / 25, k = tid % 25;
    float s = 0.f;
    for (int c = 0; c < DIMH; ++c)
      s += r_w[c] * encode_w[c * 50 + i * 25 + k];
    weff[i][k] = s;
  }
  if (tid == 64) {
    float s = 0.f;
    for (int c = 0; c < DIMH; ++c) s += r_w[c] * encode_b[c];
    *beff = s;
  }
  __syncthreads();
  if (tid < 100) {
    int val = tid / 25, k = tid % 25;
    float t = 0.f;
    if (val < 3) t = weff[0][k] * emb[val * 2] + weff[1][k] * emb[val * 2 + 1];
    T[val * 25 + k] = t;  // row 3 == 0 (padding sentinel)
  }
}

// ---------------- rq: r = table-conv(maze), q0 = conv5x5(r, q_w) -----------
__global__ __launch_bounds__(512) void rq_kernel(
    const int* __restrict__ maze, const float* __restrict__ Tg,
    const float* __restrict__ beffg, const float* __restrict__ q_w,
    float* __restrict__ q0g) {
  __shared__ float Ts[4][25];
  __shared__ float bsh;
  __shared__ v2f qw2[25][4];
  __shared__ unsigned char mzt[24][68];
  __shared__ float rt[20][68];

  int tid = threadIdx.x;
  int b = blockIdx.y, A0 = blockIdx.x * 16;

  if (tid < 100) Ts[tid / 25][tid % 25] = Tg[tid];
  if (tid == 100) bsh = *beffg;
  if (tid >= 128 && tid < 228) {
    int t2 = tid - 128;
    int k = t2 >> 2, j = t2 & 3;
    qw2[k][j] = (v2f){q_w[(2 * j) * 25 + k], q_w[(2 * j + 1) * 25 + k]};
  }
  for (int i = tid; i < 24 * 68; i += 512) {
    int mr = i / 68, mc = i % 68;
    int gy = A0 - 4 + mr, gx = mc - 2;
    unsigned char v = 3;
    if (gy >= 0 && gy < 64 && gx >= 0 && gx < 64)
      v = (unsigned char)maze[(b * 64 + gy) * 64 + gx];
    mzt[mr][mc] = v;
  }
  __syncthreads();
  // r tile rows [A0-2, A0+18): r(A0-2+rr, cc-2) taps mzt[rr+ky][cc-2+kx]
  for (int i = tid; i < 20 * 68; i += 512) {
    int rr = i / 68, cc = i % 68;
    int gy = A0 - 2 + rr, gx = cc - 2;
    float v = 0.f;
    if (gy >= 0 && gy < 64 && gx >= 0 && gx < 64) {
      v = bsh;
#pragma unroll
      for (int ky = 0; ky < 5; ++ky)
#pragma unroll
        for (int kx = 0; kx < 5; ++kx)
          v += Ts[mzt[rr + ky][cc - 2 + kx]][ky * 5 + kx];
    }
    rt[rr][cc] = v;
  }
  __syncthreads();
  for (int i = tid; i < 16 * 64; i += 512) {
    int ly = i >> 6, gx = i & 63;
    int gy = A0 + ly;
    v2f acc[4];
#pragma unroll
    for (int j = 0; j < 4; ++j) acc[j] = (v2f){0.f, 0.f};
#pragma unroll
    for (int ky = 0; ky < 5; ++ky)
#pragma unroll
      for (int kx = 0; kx < 5; ++kx) {
        int k = ky * 5 + kx;
        float vv = rt[ly + ky][gx + kx];
        v2f vv2 = (v2f){vv, vv};
#pragma unroll
        for (int j = 0; j < 4; ++j) acc[j] += qw2[k][j] * vv2;
      }
    float* dst = q0g + ((size_t)(b * 4096 + gy * 64 + gx)) * NHAT;
    ((float4*)dst)[0] = make_float4(acc[0].x, acc[0].y, acc[1].x, acc[1].y);
    ((float4*)dst)[1] = make_float4(acc[2].x, acc[2].y, acc[3].x, acc[3].y);
  }
}

// =============== vi: 10 fused VI steps + projection =================
// Block (512 thr = 8 waves) owns rows [a0, a0+8); grid 512 = 2 blk/CU.
// Wave = (slot = wave>>1, half = wave&1); pair rows r0 = s+2*slot+8i, r0+1;
// each wave does 4 channels (100 weight floats in regs/AGPRs). Half-combine:
// half0 writes vbuf[cur^1] direct; barrier; half1 RMW-max with hm[]; barrier.
// lr = r - a0 + 20; vbuf rows [0,49). LDS = 2*49*68*4 + 800 = 27.4 KB.
__global__ __launch_bounds__(512, 2) void vi_kernel(
    const float* __restrict__ q0g, const float* __restrict__ w,
    const float* __restrict__ fc_w, float* __restrict__ out) {
  __shared__ __align__(16) float vbuf[2][49][68];  // 26.6 KB
  __shared__ v2f wl2[25][4];

  int tid = threadIdx.x;
  int b = blockIdx.y, a0 = blockIdx.x * 8;
  int wave = tid >> 6, gx = tid & 63;
  int half = wave & 1, slot = wave >> 1;

  if (tid < 100) {
    int k = tid >> 2, j = tid & 3;
    wl2[k][j] = (v2f){w[(2 * j) * 25 + k], w[(2 * j + 1) * 25 + k]};
  }
  for (int i = tid; i < 2 * 49 * 68; i += 512) ((float*)vbuf)[i] = 0.f;
  __syncthreads();

  // this wave's 4 channels -> 50 v2f = 100 floats in registers/AGPRs
  v2f wr0[25], wr1[25];
#pragma unroll
  for (int k = 0; k < 25; ++k) {
    wr0[k] = wl2[k][2 * half];
    wr1[k] = wl2[k][2 * half + 1];
  }

  const float* q0b = q0g + (size_t)b * 4096 * NHAT;
  int cur = 0;

  // v0 = max_c q0 on [a0-20, a0+28): full 8ch per lane, waves stride 8 rows
  {
    int s = max(0, a0 - 20), e = min(64, a0 + 28);
    for (int r = s + wave; r < e; r += 8) {
      const float4* p = (const float4*)(q0b + ((size_t)r * 64 + gx) * NHAT);
      float4 f0 = p[0], f1 = p[1];
      float m = fmaxf(fmaxf(fmaxf(f0.x, f0.y), fmaxf(f0.z, f0.w)),
                      fmaxf(fmaxf(f1.x, f1.y), fmaxf(f1.z, f1.w)));
      vbuf[0][r - a0 + 20][gx + 2] = m;
    }
  }
  __syncthreads();

  for (int t = 1; t <= 9; ++t) {
    int hh = 2 * (10 - t);
    int s = max(0, a0 - hh), e = min(64, a0 + 8 + hh);
    float hm[12];  // half1's row maxes across pairs (<=6 pairs)
    int cnt = 0;
    // phase A: each wave -> half-max for row pair (r0, r0+1), its 4 channels
    for (int r0 = s + 2 * slot; r0 < e; r0 += 8) {
      int r1 = r0 + 1;  // may be >= e (write guarded)
      int lr0 = r0 - a0 + 20;
      const float4* p0 =
          (const float4*)(q0b + ((size_t)r0 * 64 + gx) * NHAT + half * 4);
      float4 qa = *p0;
      float4 qb = make_float4(0.f, 0.f, 0.f, 0.f);
      if (r1 < e)
        qb = *(const float4*)(q0b + ((size_t)r1 * 64 + gx) * NHAT + half * 4);
      v2f A0 = (v2f){0.f, 0.f}, A1 = (v2f){0.f, 0.f};
      v2f B0 = (v2f){0.f, 0.f}, B1 = (v2f){0.f, 0.f};
      // 6 input rows serve both outputs: r0 uses jj=0..4, r1 uses jj=1..5
#pragma unroll
      for (int jj = 0; jj < 6; ++jj) {
        const float* row = &vbuf[cur][lr0 - 2 + jj][gx];
#pragma unroll
        for (int kx = 0; kx < 5; ++kx) {
          float vv = row[kx];
          v2f vv2 = (v2f){vv, vv};
          if (jj < 5) {
            int k = jj * 5 + kx;
            A0 += wr0[k] * vv2;
            A1 += wr1[k] * vv2;
          }
          if (jj >= 1) {
            int k = (jj - 1) * 5 + kx;
            B0 += wr0[k] * vv2;
            B1 += wr1[k] * vv2;
          }
        }
      }
      A0 += (v2f){qa.x, qa.y};
      A1 += (v2f){qa.z, qa.w};
      B0 += (v2f){qb.x, qb.y};
      B1 += (v2f){qb.z, qb.w};
      float m0 = fmaxf(fmaxf(A0.x, A0.y), fmaxf(A1.x, A1.y));
      float m1 = fmaxf(fmaxf(B0.x, B0.y), fmaxf(B1.x, B1.y));
      if (half == 0) {
        vbuf[cur ^ 1][lr0][gx + 2] = m0;
        if (r1 < e) vbuf[cur ^ 1][lr0 + 1][gx + 2] = m1;
      } else {
        hm[cnt] = m0;
        hm[cnt + 1] = m1;
      }
      cnt += 2;
    }
    __syncthreads();
    // phase A2: half1 RMW-maxes its rows into vbuf[cur^1]
    if (half == 1) {
      cnt = 0;
      for (int r0 = s + 2 * slot; r0 < e; r0 += 8) {
        int lr0 = r0 - a0 + 20;
        vbuf[cur ^ 1][lr0][gx + 2] =
            fmaxf(vbuf[cur ^ 1][lr0][gx + 2], hm[cnt]);
        if (r0 + 1 < e)
          vbuf[cur ^ 1][lr0 + 1][gx + 2] =
              fmaxf(vbuf[cur ^ 1][lr0 + 1][gx + 2], hm[cnt + 1]);
        cnt += 2;
      }
    }
    __syncthreads();
    cur ^= 1;
  }

  // final step t=10 fused with projection: rows [a0, a0+8), one pair per slot
  float fcp[4][4];
#pragma unroll
  for (int a = 0; a < 4; ++a)
#pragma unroll
    for (int cc = 0; cc < 4; ++cc) fcp[a][cc] = fc_w[a * 8 + 4 * half + cc];
  float* proj = (float*)&vbuf[cur ^ 1][0][0];  // dead buffer, 8KB reuse

  {
    int r0 = a0 + 2 * slot;
    int r1 = r0 + 1;
    int lr0 = r0 - a0 + 20;
    const float4* p0 =
        (const float4*)(q0b + ((size_t)r0 * 64 + gx) * NHAT + half * 4);
    float4 qa = *p0;
    float4 qb =
        *(const float4*)(q0b + ((size_t)r1 * 64 + gx) * NHAT + half * 4);
    v2f A0 = (v2f){0.f, 0.f}, A1 = (v2f){0.f, 0.f};
    v2f B0 = (v2f){0.f, 0.f}, B1 = (v2f){0.f, 0.f};
#pragma unroll
    for (int jj = 0; jj < 6; ++jj) {
      const float* row = &vbuf[cur][lr0 - 2 + jj][gx];
#pragma unroll
      for (int kx = 0; kx < 5; ++kx) {
        float vv = row[kx];
        v2f vv2 = (v2f){vv, vv};
        if (jj < 5) {
          int k = jj * 5 + kx;
          A0 += wr0[k] * vv2;
          A1 += wr1[k] * vv2;
        }
        if (jj >= 1) {
          int k = (jj - 1) * 5 + kx;
          B0 += wr0[k] * vv2;
          B1 += wr1[k] * vv2;
        }
      }
    }
    float q0v = A0.x + qa.x, q1v = A0.y + qa.y;
    float q2v = A1.x + qa.z, q3v = A1.y + qa.w;
    float4 pa;
    pa.x = fcp[0][0] * q0v + fcp[0][1] * q1v + fcp[0][2] * q2v + fcp[0][3] * q3v;
    pa.y = fcp[1][0] * q0v + fcp[1][1] * q1v + fcp[1][2] * q2v + fcp[1][3] * q3v;
    pa.z = fcp[2][0] * q0v + fcp[2][1] * q1v + fcp[2][2] * q2v + fcp[2][3] * q3v;
    pa.w = fcp[3][0] * q0v + fcp[3][1] * q1v + fcp[3][2] * q2v + fcp[3][3] * q3v;
    q0v = B0.x + qb.x; q1v = B0.y + qb.y;
    q2v = B1.x + qb.z; q3v = B1.y + qb.w;
    float4 pb;
    pb.x = fcp[0][0] * q0v + fcp[0][1] * q1v + fcp[0][2] * q2v + fcp[0][3] * q3v;
    pb.y = fcp[1][0] * q0v + fcp[1][1] * q1v + fcp[1][2] * q2v + fcp[1][3] * q3v;
    pb.z = fcp[2][0] * q0v + fcp[2][1] * q1v + fcp[2][2] * q2v + fcp[2][3] * q3v;
    pb.w = fcp[3][0] * q0v + fcp[3][1] * q1v + fcp[3][2] * q2v + fcp[3][3] * q3v;
    int i0 = 2 * slot, i1 = 2 * slot + 1;
    if (half == 1) {
      *(float4*)&proj[(i0 * 64 + gx) * 4] = pa;
      *(float4*)&proj[(i1 * 64 + gx) * 4] = pb;
    }
    __syncthreads();
    if (half == 0) {
      float4 oa = *(const float4*)&proj[(i0 * 64 + gx) * 4];
      float4 ob = *(const float4*)&proj[(i1 * 64 + gx) * 4];
      oa.x += pa.x; oa.y += pa.y; oa.z += pa.z; oa.w += pa.w;
      ob.x += pb.x; ob.y += pb.y; ob.z += pb.z; ob.w += pb.w;
      *(float4*)&out[((size_t)((b * 64 + r0) * 64 + gx)) * 4] = oa;
      *(float4*)&out[((size_t)((b * 64 + r1) * 64 + gx)) * 4] = ob;
    }
  }
}

extern "C" void kernel_launch(void* const* d_in, const int* in_sizes, int n_in,
                              void* d_out, int out_size, void* d_ws, size_t ws_size,
                              hipStream_t stream) {
  const int* maze = (const int*)d_in[0];
  const float* emb = (const float*)d_in[1];
  const float* encode_w = (const float*)d_in[2];
  const float* encode_b = (const float*)d_in[3];
  const float* r_w = (const float*)d_in[4];
  const float* q_w = (const float*)d_in[5];
  const float* w = (const float*)d_in[6];
  const float* fc_w = (const float*)d_in[7];
  float* out = (float*)d_out;

  float* wsf = (float*)d_ws;
  float* T = wsf;            // 100 floats
  float* beff = wsf + 100;   // 1 float
  float* q0 = wsf + 128;     // 8 MB

  prep_kernel<<<1, 128, 0, stream>>>(emb, encode_w, encode_b, r_w, T, beff);
  rq_kernel<<<dim3(4, 64), 512, 0, stream>>>(maze, T, beff, q_w, q0);
  vi_kernel<<<dim3(8, 64), 512, 0, stream>>>(q0, w, fc_w, out);
}

// Round 17
// 122.825 us; speedup vs baseline: 1.2088x; 1.1843x over previous
//
#include <hip/hip_runtime.h>
#include <hip/hip_bf16.h>

// Nav_64939905516231 (VIN value iteration), MI355X gfx950.
// B=64,H=W=64,dim_h=150,n_hat=8,n_act=4,K=10. fp32 in/out, maze int32.
// Collapses: r = conv5x5(m,W_eff)+b_eff (150ch folded); q_t = q0 + conv5x5(v,w).
// prep (1 blk) -> rq (r+q0) -> vi (10 fused steps + projection).
// Facts: 1024-thr => VGPR 64 (GB spills); 512-thr => VGPR<=128 + AGPR overflow
// (100-float weight arrays live spill-free). Occupancy pinned at 8 waves/CU
// regardless of LDS (R16 falsified the LDS-cap theory; grid 512 just
// serializes + pays halo redundancy). Binding pipe at OWN=16/grid256: per-CU
// LDS issue (30 ds_read_b32 per wave-iter ~ 25us floor; VALU ~9us).
// R17: 4 px/lane phase A -- tap patch read as 2x ds_read_b128 per tap row
// (16B aligned, 2-way banks = free): 10 b128 per lane-row vs 30 b32 ->
// LDS floor ~11us. Channel-split halves combine via tmp (b128 writes).

#define NHAT 8
#define DIMH 150

typedef float v2f __attribute__((ext_vector_type(2)));

// ---------------- prep: T[4][25] tap table + b_eff (1 block) ----------------
__global__ __launch_bounds__(128) void prep_kernel(
    const float* __restrict__ emb, const float* __restrict__ encode_w,
    const float* __restrict__ encode_b, const float* __restrict__ r_w,
    float* __restrict__ T, float* __restrict__ beff) {
  __shared__ float weff[2][25];
  int tid = threadIdx.x;
  if (tid < 50) {
    int i = tid / 25, k = tid % 25;
    float s = 0.f;
    for (int c = 0; c < DIMH; ++c)
      s += r_w[c] * encode_w[c * 50 + i * 25 + k];
    weff[i][k] = s;
  }
  if (tid == 64) {
    float s = 0.f;
    for (int c = 0; c < DIMH; ++c) s += r_w[c] * encode_b[c];
    *beff = s;
  }
  __syncthreads();
  if (tid < 100) {
    int val = tid / 25, k = tid % 25;
    float t = 0.f;
    if (val < 3) t = weff[0][k] * emb[val * 2] + weff[1][k] * emb[val * 2 + 1];
    T[val * 25 + k] = t;  // row 3 == 0 (padding sentinel)
  }
}

// ---------------- rq: r = table-conv(maze), q0 = conv5x5(r, q_w) -----------
__global__ __launch_bounds__(512) void rq_kernel(
    const int* __restrict__ maze, const float* __restrict__ Tg,
    const float* __restrict__ beffg, const float* __restrict__ q_w,
    float* __restrict__ q0g) {
  __shared__ float Ts[4][25];
  __shared__ float bsh;
  __shared__ v2f qw2[25][4];
  __shared__ unsigned char mzt[24][68];
  __shared__ float rt[20][68];

  int tid = threadIdx.x;
  int b = blockIdx.y, A0 = blockIdx.x * 16;

  if (tid < 100) Ts[tid / 25][tid % 25] = Tg[tid];
  if (tid == 100) bsh = *beffg;
  if (tid >= 128 && tid < 228) {
    int t2 = tid - 128;
    int k = t2 >> 2, j = t2 & 3;
    qw2[k][j] = (v2f){q_w[(2 * j) * 25 + k], q_w[(2 * j + 1) * 25 + k]};
  }
  for (int i = tid; i < 24 * 68; i += 512) {
    int mr = i / 68, mc = i % 68;
    int gy = A0 - 4 + mr, gx = mc - 2;
    unsigned char v = 3;
    if (gy >= 0 && gy < 64 && gx >= 0 && gx < 64)
      v = (unsigned char)maze[(b * 64 + gy) * 64 + gx];
    mzt[mr][mc] = v;
  }
  __syncthreads();
  for (int i = tid; i < 20 * 68; i += 512) {
    int rr = i / 68, cc = i % 68;
    int gy = A0 - 2 + rr, gx = cc - 2;
    float v = 0.f;
    if (gy >= 0 && gy < 64 && gx >= 0 && gx < 64) {
      v = bsh;
#pragma unroll
      for (int ky = 0; ky < 5; ++ky)
#pragma unroll
        for (int kx = 0; kx < 5; ++kx)
          v += Ts[mzt[rr + ky][cc - 2 + kx]][ky * 5 + kx];
    }
    rt[rr][cc] = v;
  }
  __syncthreads();
  for (int i = tid; i < 16 * 64; i += 512) {
    int ly = i >> 6, gx = i & 63;
    int gy = A0 + ly;
    v2f acc[4];
#pragma unroll
    for (int j = 0; j < 4; ++j) acc[j] = (v2f){0.f, 0.f};
#pragma unroll
    for (int ky = 0; ky < 5; ++ky)
#pragma unroll
      for (int kx = 0; kx < 5; ++kx) {
        int k = ky * 5 + kx;
        float vv = rt[ly + ky][gx + kx];
        v2f vv2 = (v2f){vv, vv};
#pragma unroll
        for (int j = 0; j < 4; ++j) acc[j] += qw2[k][j] * vv2;
      }
    float* dst = q0g + ((size_t)(b * 4096 + gy * 64 + gx)) * NHAT;
    ((float4*)dst)[0] = make_float4(acc[0].x, acc[0].y, acc[1].x, acc[1].y);
    ((float4*)dst)[1] = make_float4(acc[2].x, acc[2].y, acc[3].x, acc[3].y);
  }
}

// =============== vi: 10 fused VI steps + projection =================
// Block (512 thr = 8 waves) owns rows [a0, a0+16); grid 256 (1 blk/CU).
// Wave = (slot = wave>>1, half = wave&1). Phase A: lane = (roff = lane>>4,
// px base i4 = 4*(lane&15)); each lane computes 4 px of row rb+roff for its
// 4 channels. Tap patch: 5 rows x 2 ds_read_b128 (cols i4..i4+7, 16B
// aligned). Half-maxes -> tmp[lr-4][half][i4..i4+3] (1 b128 write).
// Phase B combines halves -> vbuf[cur^1]. lr = r - a0 + 22; vbuf rows [0,60).
__global__ __launch_bounds__(512, 2) void vi_kernel(
    const float* __restrict__ q0g, const float* __restrict__ w,
    const float* __restrict__ fc_w, float* __restrict__ out) {
  __shared__ __align__(16) float vbuf[2][60][68];  // 32.6 KB
  __shared__ __align__(16) float tmp[52][2][64];   // 26.6 KB (reused in proj)
  __shared__ v2f wl2[25][4];

  int tid = threadIdx.x;
  int b = blockIdx.y, a0 = blockIdx.x * 16;
  int wave = tid >> 6, lane = tid & 63;
  int half = wave & 1, slot = wave >> 1;
  int roff = lane >> 4, i4 = (lane & 15) * 4;

  if (tid < 100) {
    int k = tid >> 2, j = tid & 3;
    wl2[k][j] = (v2f){w[(2 * j) * 25 + k], w[(2 * j + 1) * 25 + k]};
  }
  for (int i = tid; i < 2 * 60 * 68; i += 512) ((float*)vbuf)[i] = 0.f;
  __syncthreads();

  // this wave's 4 channels -> 50 v2f = 100 floats (regs/AGPRs, no spill)
  v2f wr0[25], wr1[25];
#pragma unroll
  for (int k = 0; k < 25; ++k) {
    wr0[k] = wl2[k][2 * half];
    wr1[k] = wl2[k][2 * half + 1];
  }

  const float* q0b = q0g + (size_t)b * 4096 * NHAT;
  int cur = 0;

  // v0 = max_c q0 on [a0-20, a0+36): full 8ch per lane, waves stride 8 rows
  {
    int s = max(0, a0 - 20), e = min(64, a0 + 36);
    int gx = lane;
    for (int r = s + wave; r < e; r += 8) {
      const float4* p = (const float4*)(q0b + ((size_t)r * 64 + gx) * NHAT);
      float4 f0 = p[0], f1 = p[1];
      float m = fmaxf(fmaxf(fmaxf(f0.x, f0.y), fmaxf(f0.z, f0.w)),
                      fmaxf(fmaxf(f1.x, f1.y), fmaxf(f1.z, f1.w)));
      vbuf[0][r - a0 + 22][gx + 2] = m;
    }
  }
  __syncthreads();

  for (int t = 1; t <= 9; ++t) {
    int hh = 2 * (10 - t);
    int s = max(0, a0 - hh), e = min(64, a0 + 16 + hh);
    // phase A: quad sweeps; lane handles 4 px of row rb+roff, 4 channels
    for (int rb = s + 4 * slot; rb < e; rb += 16) {
      int r = rb + roff;
      if (r < e) {
        int lr = r - a0 + 22;
        const float4* qp =
            (const float4*)(q0b + ((size_t)r * 64 + i4) * NHAT + half * 4);
        float4 qv0 = qp[0], qv1 = qp[2], qv2 = qp[4], qv3 = qp[6];
        v2f aA[4], aB[4];
        aA[0] = (v2f){qv0.x, qv0.y}; aB[0] = (v2f){qv0.z, qv0.w};
        aA[1] = (v2f){qv1.x, qv1.y}; aB[1] = (v2f){qv1.z, qv1.w};
        aA[2] = (v2f){qv2.x, qv2.y}; aB[2] = (v2f){qv2.z, qv2.w};
        aA[3] = (v2f){qv3.x, qv3.y}; aB[3] = (v2f){qv3.z, qv3.w};
#pragma unroll
        for (int jj = 0; jj < 5; ++jj) {
          const float* row = &vbuf[cur][lr - 2 + jj][i4];
          float4 fa = *(const float4*)row;
          float4 fb = *(const float4*)(row + 4);
          float f[8] = {fa.x, fa.y, fa.z, fa.w, fb.x, fb.y, fb.z, fb.w};
#pragma unroll
          for (int kx = 0; kx < 5; ++kx) {
            int k = jj * 5 + kx;
            v2f w0 = wr0[k], w1 = wr1[k];
#pragma unroll
            for (int j = 0; j < 4; ++j) {
              v2f vv2 = (v2f){f[j + kx], f[j + kx]};
              aA[j] += w0 * vv2;
              aB[j] += w1 * vv2;
            }
          }
        }
        float m0 = fmaxf(fmaxf(aA[0].x, aA[0].y), fmaxf(aB[0].x, aB[0].y));
        float m1 = fmaxf(fmaxf(aA[1].x, aA[1].y), fmaxf(aB[1].x, aB[1].y));
        float m2 = fmaxf(fmaxf(aA[2].x, aA[2].y), fmaxf(aB[2].x, aB[2].y));
        float m3 = fmaxf(fmaxf(aA[3].x, aA[3].y), fmaxf(aB[3].x, aB[3].y));
        *(float4*)&tmp[lr - 4][half][i4] = make_float4(m0, m1, m2, m3);
      }
    }
    __syncthreads();
    // phase B: combine halves -> vbuf[cur^1]
    int n = e - s;
    for (int idx = tid; idx < n * 64; idx += 512) {
      int rr = idx >> 6, px = idx & 63;
      int lr2 = s - a0 + 22 + rr;
      vbuf[cur ^ 1][lr2][px + 2] =
          fmaxf(tmp[lr2 - 4][0][px], tmp[lr2 - 4][1][px]);
    }
    __syncthreads();
    cur ^= 1;
  }

  // final step t=10 + projection: rows [a0, a0+16), one quad sweep
  float fcp[4][4];
#pragma unroll
  for (int a = 0; a < 4; ++a)
#pragma unroll
    for (int cc = 0; cc < 4; ++cc) fcp[a][cc] = fc_w[a * 8 + 4 * half + cc];
  float* ptmp = (float*)tmp;  // [16][64][4] = 16 KB

  {
    int r = a0 + 4 * slot + roff;  // always in [a0, a0+16)
    int lr = r - a0 + 22;
    const float4* qp =
        (const float4*)(q0b + ((size_t)r * 64 + i4) * NHAT + half * 4);
    float4 qv0 = qp[0], qv1 = qp[2], qv2 = qp[4], qv3 = qp[6];
    v2f aA[4], aB[4];
    aA[0] = (v2f){qv0.x, qv0.y}; aB[0] = (v2f){qv0.z, qv0.w};
    aA[1] = (v2f){qv1.x, qv1.y}; aB[1] = (v2f){qv1.z, qv1.w};
    aA[2] = (v2f){qv2.x, qv2.y}; aB[2] = (v2f){qv2.z, qv2.w};
    aA[3] = (v2f){qv3.x, qv3.y}; aB[3] = (v2f){qv3.z, qv3.w};
#pragma unroll
    for (int jj = 0; jj < 5; ++jj) {
      const float* row = &vbuf[cur][lr - 2 + jj][i4];
      float4 fa = *(const float4*)row;
      float4 fb = *(const float4*)(row + 4);
      float f[8] = {fa.x, fa.y, fa.z, fa.w, fb.x, fb.y, fb.z, fb.w};
#pragma unroll
      for (int kx = 0; kx < 5; ++kx) {
        int k = jj * 5 + kx;
        v2f w0 = wr0[k], w1 = wr1[k];
#pragma unroll
        for (int j = 0; j < 4; ++j) {
          v2f vv2 = (v2f){f[j + kx], f[j + kx]};
          aA[j] += w0 * vv2;
          aB[j] += w1 * vv2;
        }
      }
    }
    float4 pp[4];
#pragma unroll
    for (int j = 0; j < 4; ++j) {
      float q0v = aA[j].x, q1v = aA[j].y, q2v = aB[j].x, q3v = aB[j].y;
      pp[j].x = fcp[0][0] * q0v + fcp[0][1] * q1v + fcp[0][2] * q2v + fcp[0][3] * q3v;
      pp[j].y = fcp[1][0] * q0v + fcp[1][1] * q1v + fcp[1][2] * q2v + fcp[1][3] * q3v;
      pp[j].z = fcp[2][0] * q0v + fcp[2][1] * q1v + fcp[2][2] * q2v + fcp[2][3] * q3v;
      pp[j].w = fcp[3][0] * q0v + fcp[3][1] * q1v + fcp[3][2] * q2v + fcp[3][3] * q3v;
    }
    if (half == 1) {
#pragma unroll
      for (int j = 0; j < 4; ++j)
        *(float4*)&ptmp[(((r - a0) * 64) + i4 + j) * 4] = pp[j];
    }
    __syncthreads();
    if (half == 0) {
#pragma unroll
      for (int j = 0; j < 4; ++j) {
        float4 o = *(const float4*)&ptmp[(((r - a0) * 64) + i4 + j) * 4];
        o.x += pp[j].x; o.y += pp[j].y; o.z += pp[j].z; o.w += pp[j].w;
        *(float4*)&out[((size_t)((b * 64 + r) * 64 + i4 + j)) * 4] = o;
      }
    }
  }
}

extern "C" void kernel_launch(void* const* d_in, const int* in_sizes, int n_in,
                              void* d_out, int out_size, void* d_ws, size_t ws_size,
                              hipStream_t stream) {
  const int* maze = (const int*)d_in[0];
  const float* emb = (const float*)d_in[1];
  const float* encode_w = (const float*)d_in[2];
  const float* encode_b = (const float*)d_in[3];
  const float* r_w = (const float*)d_in[4];
  const float* q_w = (const float*)d_in[5];
  const float* w = (const float*)d_in[6];
  const float* fc_w = (const float*)d_in[7];
  float* out = (float*)d_out;

  float* wsf = (float*)d_ws;
  float* T = wsf;            // 100 floats
  float* beff = wsf + 100;   // 1 float
  float* q0 = wsf + 128;     // 8 MB

  prep_kernel<<<1, 128, 0, stream>>>(emb, encode_w, encode_b, r_w, T, beff);
  rq_kernel<<<dim3(4, 64), 512, 0, stream>>>(maze, T, beff, q_w, q0);
  vi_kernel<<<dim3(4, 64), 512, 0, stream>>>(q0, w, fc_w, out);
}